// Round 10
// baseline (589.054 us; speedup 1.0000x reference)
//
#include <hip/hip_runtime.h>
#include <hip/hip_bf16.h>
#include <stdint.h>

#define DD 32       // input dim
#define HH 64       // hidden dim
#define HSTRIDE 80  // LDS h-row stride in elems (160B)
#define LOG2E 1.44269504088896340736f

typedef float f32x4 __attribute__((ext_vector_type(4)));
typedef short s16x8 __attribute__((ext_vector_type(8)));

// Single-instruction packed f32->bf16 (RNE). Low 16 bits = lo, high = hi.
__device__ __forceinline__ uint32_t cvtpk(float lo, float hi) {
  uint32_t r;
  asm("v_cvt_pk_bf16_f32 %0, %1, %2" : "=v"(r) : "v"(lo), "v"(hi));
  return r;
}

// Relaxed workgroup barrier: order LDS ops only (x-prefetch global loads stay
// in flight). sched_barrier(0) pins the compiler: nothing crosses this point.
#define BAR() do {                                                    \
  asm volatile("s_waitcnt lgkmcnt(0)\n\ts_barrier" ::: "memory");     \
  __builtin_amdgcn_sched_barrier(0);                                  \
} while (0)

// 512 blocks x 4 waves; block handles 4 batch rows = 2 chains x 2 rows.
// Wave w owns cols 16w..16w+15 (4 gate-tiles) for BOTH chains (weights shared).
// A-row content batch=row>>3 (dup x8) => D rows 4lq+r map to batch lq>>1 for
// all r. Lane (lr,lq): chain = lq&1, batch = lq>>1, col = 16w+lr -> exactly
// ONE cell per lane (10 trans), gates via 4 cndmask on acc[j][0].
__global__ __launch_bounds__(256, 2)
void lstm_fused(const float* __restrict__ x,
                const float* __restrict__ W_ih,
                const float* __restrict__ W_hh,
                const float* __restrict__ b_ih,
                const float* __restrict__ b_hh,
                const float* __restrict__ fc_W,
                const float* __restrict__ fc_b,
                float* __restrict__ out,
                int T)
{
  const int tid  = threadIdx.x;
  const int w    = tid >> 6;     // wave 0..3 -> col group 16w
  const int lane = tid & 63;
  const int lr   = lane & 15;    // A/D col index within tile
  const int lq   = lane >> 4;    // k-group 0..3
  const int arow = lr >> 3;      // batch row content of A slot (dup x8): 0/1
  const int bm   = blockIdx.x * 4;

  // [buf][chain][row*HSTRIDE], chain stride 2*HSTRIDE
  __shared__ __align__(16) uint16_t hbuf[2][2][2 * HSTRIDE];

  // ---- persistent weights (shared by both chains): tile j = gate j.
  // pre-scaled by log2e (2*log2e for g-gate).
  s16x8 Bx[4], Bh0[4], Bh1[4];
  f32x4 biasv[4];
  #pragma unroll
  for (int j = 0; j < 4; ++j) {
    const int n = 64 * j + 16 * w + lr;
    const float sc = (j == 2) ? (2.0f * LOG2E) : LOG2E;
    {
      const float* p = W_ih + n * DD + lq * 8;
      f32x4 a = *(const f32x4*)p;
      f32x4 b = *(const f32x4*)(p + 4);
      union { uint32_t u[4]; s16x8 s; } pk;
      pk.u[0] = cvtpk(a[0]*sc, a[1]*sc); pk.u[1] = cvtpk(a[2]*sc, a[3]*sc);
      pk.u[2] = cvtpk(b[0]*sc, b[1]*sc); pk.u[3] = cvtpk(b[2]*sc, b[3]*sc);
      Bx[j] = pk.s;
    }
    {
      const float* p = W_hh + n * HH + lq * 8;
      f32x4 a = *(const f32x4*)p;
      f32x4 b = *(const f32x4*)(p + 4);
      union { uint32_t u[4]; s16x8 s; } pk;
      pk.u[0] = cvtpk(a[0]*sc, a[1]*sc); pk.u[1] = cvtpk(a[2]*sc, a[3]*sc);
      pk.u[2] = cvtpk(b[0]*sc, b[1]*sc); pk.u[3] = cvtpk(b[2]*sc, b[3]*sc);
      Bh0[j] = pk.s;
    }
    {
      const float* p = W_hh + n * HH + 32 + lq * 8;
      f32x4 a = *(const f32x4*)p;
      f32x4 b = *(const f32x4*)(p + 4);
      union { uint32_t u[4]; s16x8 s; } pk;
      pk.u[0] = cvtpk(a[0]*sc, a[1]*sc); pk.u[1] = cvtpk(a[2]*sc, a[3]*sc);
      pk.u[2] = cvtpk(b[0]*sc, b[1]*sc); pk.u[3] = cvtpk(b[2]*sc, b[3]*sc);
      Bh1[j] = pk.s;
    }
    const float bb = (b_ih[n] + b_hh[n]) * sc;
    biasv[j] = (f32x4){bb, bb, bb, bb};
  }

  for (int i = tid; i < 2 * 2 * 2 * HSTRIDE; i += 256) ((uint16_t*)hbuf)[i] = 0;

  float c = 0.f;  // this lane's single cell: (chain lq&1, batch lq>>1, col 16w+lr)

  // hoisted LDS offsets
  const int roff0 = arow * HSTRIDE + 8 * lq;                 // within a chain buf
  const int roff1 = roff0 + 32;
  const int woff  = (lq & 1) * (2 * HSTRIDE) + (lq >> 1) * HSTRIDE + 16 * w + lr;

  // 2-deep x prefetch per chain (addresses dup x8; coalescer dedups)
  const float* xbA = x + (size_t)(bm +     arow) * (size_t)T * DD + lq * 8;
  const float* xbB = x + (size_t)(bm + 2 + arow) * (size_t)T * DD + lq * 8;
  f32x4 xa0A = *(const f32x4*)xbA;        f32x4 xb0A = *(const f32x4*)(xbA + 4);
  f32x4 xa1A = *(const f32x4*)(xbA + DD); f32x4 xb1A = *(const f32x4*)(xbA + DD + 4);
  f32x4 xa0B = *(const f32x4*)xbB;        f32x4 xb0B = *(const f32x4*)(xbB + 4);
  f32x4 xa1B = *(const f32x4*)(xbB + DD); f32x4 xb1B = *(const f32x4*)(xbB + DD + 4);
  const float* xpA = xbA + 2 * DD;
  const float* xpB = xbB + 2 * DD;

  __syncthreads();

  auto step = [&](f32x4& xaA, f32x4& xbAv, f32x4& xaB, f32x4& xbBv, bool pf,
                  const uint16_t* hr, uint16_t* hw) {
    BAR();  // prev step's h writes visible; global x loads stay in flight

    // h reads, both chains (chain B buffer at +2*HSTRIDE)
    s16x8 a0A = *(const s16x8*)(hr + roff0);
    s16x8 a1A = *(const s16x8*)(hr + roff1);
    s16x8 a0B = *(const s16x8*)(hr + 2 * HSTRIDE + roff0);
    s16x8 a1B = *(const s16x8*)(hr + 2 * HSTRIDE + roff1);

    // pack both chains' x into A fragments, then issue t+2 prefetches
    union { uint32_t u[4]; s16x8 s; } axA, axB;
    axA.u[0] = cvtpk(xaA[0], xaA[1]);   axA.u[1] = cvtpk(xaA[2], xaA[3]);
    axA.u[2] = cvtpk(xbAv[0], xbAv[1]); axA.u[3] = cvtpk(xbAv[2], xbAv[3]);
    axB.u[0] = cvtpk(xaB[0], xaB[1]);   axB.u[1] = cvtpk(xaB[2], xaB[3]);
    axB.u[2] = cvtpk(xbBv[0], xbBv[1]); axB.u[3] = cvtpk(xbBv[2], xbBv[3]);
    if (pf) {
      xaA = *(const f32x4*)xpA; xbAv = *(const f32x4*)(xpA + 4); xpA += DD;
      xaB = *(const f32x4*)xpB; xbBv = *(const f32x4*)(xpB + 4); xpB += DD;
    }

    // MFMAs: x-part then h-parts, two independent chains pipeline
    f32x4 accA[4], accB[4];
    #pragma unroll
    for (int j = 0; j < 4; ++j)
      accA[j] = __builtin_amdgcn_mfma_f32_16x16x32_bf16(axA.s, Bx[j], biasv[j], 0, 0, 0);
    #pragma unroll
    for (int j = 0; j < 4; ++j)
      accB[j] = __builtin_amdgcn_mfma_f32_16x16x32_bf16(axB.s, Bx[j], biasv[j], 0, 0, 0);
    #pragma unroll
    for (int j = 0; j < 4; ++j)
      accA[j] = __builtin_amdgcn_mfma_f32_16x16x32_bf16(a0A, Bh0[j], accA[j], 0, 0, 0);
    #pragma unroll
    for (int j = 0; j < 4; ++j)
      accB[j] = __builtin_amdgcn_mfma_f32_16x16x32_bf16(a0B, Bh0[j], accB[j], 0, 0, 0);
    #pragma unroll
    for (int j = 0; j < 4; ++j)
      accA[j] = __builtin_amdgcn_mfma_f32_16x16x32_bf16(a1A, Bh1[j], accA[j], 0, 0, 0);
    #pragma unroll
    for (int j = 0; j < 4; ++j)
      accB[j] = __builtin_amdgcn_mfma_f32_16x16x32_bf16(a1B, Bh1[j], accB[j], 0, 0, 0);

    // chain select: lane's cell belongs to chain lq&1 (4 cndmask)
    const bool cb = (lq & 1) != 0;
    float g0 = cb ? accB[0][0] : accA[0][0];
    float g1 = cb ? accB[1][0] : accA[1][0];
    float g2 = cb ? accB[2][0] : accA[2][0];
    float g3 = cb ? accB[3][0] : accA[3][0];

    // single-cell LSTM update (weights pre-scaled by log2e)
    float ig = __builtin_amdgcn_rcpf(1.f + __builtin_amdgcn_exp2f(-g0));
    float fg = __builtin_amdgcn_rcpf(1.f + __builtin_amdgcn_exp2f(-g1));
    float gt = 1.f - 2.f * __builtin_amdgcn_rcpf(1.f + __builtin_amdgcn_exp2f(g2));
    float og = __builtin_amdgcn_rcpf(1.f + __builtin_amdgcn_exp2f(-g3));
    c = fg * c + ig * gt;
    float tc = 1.f - 2.f * __builtin_amdgcn_rcpf(
                 1.f + __builtin_amdgcn_exp2f((2.0f * LOG2E) * c));
    float hv = og * tc;
    hw[woff] = (uint16_t)cvtpk(hv, hv);  // one b16 write per lane
  };

  for (int t = 0; t < T - 2; t += 2) {
    step(xa0A, xb0A, xa0B, xb0B, true, hbuf[0][0], hbuf[1][0]);
    step(xa1A, xb1A, xa1B, xb1B, true, hbuf[1][0], hbuf[0][0]);
  }
  step(xa0A, xb0A, xa0B, xb0B, false, hbuf[0][0], hbuf[1][0]);
  step(xa1A, xb1A, xa1B, xb1B, false, hbuf[1][0], hbuf[0][0]);

  __syncthreads();  // final h (bf16) in hbuf[0][chain], linear [row][col]

  // ---- epilogue: logits = h_last @ fc_W^T + fc_b (4 rows x 10 cols) ----
  if (tid < 40) {
    const int m = tid / 10, cl = tid % 10;   // m: 0..3 -> chain m>>1, row m&1
    float s = fc_b[cl];
    const float* wr = fc_W + cl * HH;
    const uint16_t* hm = hbuf[0][m >> 1] + (m & 1) * HSTRIDE;
    #pragma unroll
    for (int k = 0; k < HH; ++k) {
      union { uint32_t u; float f; } v;
      v.u = (uint32_t)hm[k] << 16;
      s += v.f * wr[k];
    }
    out[(size_t)(bm + m) * 10 + cl] = s;
  }
}

extern "C" void kernel_launch(void* const* d_in, const int* in_sizes, int n_in,
                              void* d_out, int out_size, void* d_ws, size_t ws_size,
                              hipStream_t stream) {
  const float* x    = (const float*)d_in[0];
  const float* W_ih = (const float*)d_in[1];
  const float* W_hh = (const float*)d_in[2];
  const float* b_ih = (const float*)d_in[3];
  const float* b_hh = (const float*)d_in[4];
  const float* fc_W = (const float*)d_in[5];
  const float* fc_b = (const float*)d_in[6];
  float* out = (float*)d_out;

  const int B = out_size / 10;            // 2048
  const int T = in_sizes[0] / (B * DD);   // 1024

  dim3 grid(B / 4), block(256);
  hipLaunchKernelGGL(lstm_fused, grid, block, 0, stream,
                     x, W_ih, W_hh, b_ih, b_hh, fc_W, fc_b, out, T);
}

// Round 11
// 389.182 us; speedup vs baseline: 1.5136x; 1.5136x over previous
//
#include <hip/hip_runtime.h>
#include <hip/hip_bf16.h>
#include <stdint.h>

#define DD 32       // input dim
#define HH 64       // hidden dim
#define HSTRIDE 80  // LDS h-row stride in elems (160B)
#define LOG2E 1.44269504088896340736f

typedef float f32x4 __attribute__((ext_vector_type(4)));
typedef short s16x8 __attribute__((ext_vector_type(8)));

// Single-instruction packed f32->bf16 (RNE). Low 16 bits = lo, high = hi.
__device__ __forceinline__ uint32_t cvtpk(float lo, float hi) {
  uint32_t r;
  asm("v_cvt_pk_bf16_f32 %0, %1, %2" : "=v"(r) : "v"(lo), "v"(hi));
  return r;
}

// Relaxed workgroup barrier: order LDS ops only (x-prefetch global loads stay
// in flight). sched_barrier(0) pins the compiler: nothing crosses this point.
#define BAR() do {                                                    \
  asm volatile("s_waitcnt lgkmcnt(0)\n\ts_barrier" ::: "memory");     \
  __builtin_amdgcn_sched_barrier(0);                                  \
} while (0)

// 256 blocks x 8 waves. Waves 0-3 = chain A (rows bm..bm+3), waves 4-7 =
// chain B (rows bm+4..bm+7). Each chain: 4 rows, A-rows dup x4 (arow=lr>>2).
// Wave (chain, w): cols 16w..16w+15 for all 4 gates = 4 N-tiles x 3 K-MFMA =
// 12 MFMA/step. D rows 4lq+r all map to batch lq => lane (lr,lq) owns cell
// (batch lq, col 16w+lr); gate j = acc[j][0]. One cell/lane, 10 trans.
// Same per-SIMD totals as R9 (24 MFMA, 2 cells) but TWO independent streams.
__global__ __launch_bounds__(512, 2)
void lstm_fused(const float* __restrict__ x,
                const float* __restrict__ W_ih,
                const float* __restrict__ W_hh,
                const float* __restrict__ b_ih,
                const float* __restrict__ b_hh,
                const float* __restrict__ fc_W,
                const float* __restrict__ fc_b,
                float* __restrict__ out,
                int T)
{
  const int tid   = threadIdx.x;
  const int wv    = tid >> 6;      // 0..7
  const int chain = wv >> 2;       // 0..1
  const int w     = wv & 3;        // col group 16w
  const int lane  = tid & 63;
  const int lr    = lane & 15;     // A/D col index within tile
  const int lq    = lane >> 4;     // k-group 0..3; ALSO this lane's batch row
  const int arow  = lr >> 2;       // batch row content of A slot (dup x4)
  const int bm    = blockIdx.x * 8;

  // [buf][chain][row*HSTRIDE]
  __shared__ __align__(16) uint16_t hbuf[2][2][4 * HSTRIDE];

  // ---- persistent weights: tile j = gate j, cols 16w..16w+15.
  // pre-scaled by log2e (2*log2e for g-gate).
  s16x8 Bx[4], Bh0[4], Bh1[4];
  f32x4 biasv[4];
  #pragma unroll
  for (int j = 0; j < 4; ++j) {
    const int n = 64 * j + 16 * w + lr;
    const float sc = (j == 2) ? (2.0f * LOG2E) : LOG2E;
    {
      const float* p = W_ih + n * DD + lq * 8;
      f32x4 a = *(const f32x4*)p;
      f32x4 b = *(const f32x4*)(p + 4);
      union { uint32_t u[4]; s16x8 s; } pk;
      pk.u[0] = cvtpk(a[0]*sc, a[1]*sc); pk.u[1] = cvtpk(a[2]*sc, a[3]*sc);
      pk.u[2] = cvtpk(b[0]*sc, b[1]*sc); pk.u[3] = cvtpk(b[2]*sc, b[3]*sc);
      Bx[j] = pk.s;
    }
    {
      const float* p = W_hh + n * HH + lq * 8;
      f32x4 a = *(const f32x4*)p;
      f32x4 b = *(const f32x4*)(p + 4);
      union { uint32_t u[4]; s16x8 s; } pk;
      pk.u[0] = cvtpk(a[0]*sc, a[1]*sc); pk.u[1] = cvtpk(a[2]*sc, a[3]*sc);
      pk.u[2] = cvtpk(b[0]*sc, b[1]*sc); pk.u[3] = cvtpk(b[2]*sc, b[3]*sc);
      Bh0[j] = pk.s;
    }
    {
      const float* p = W_hh + n * HH + 32 + lq * 8;
      f32x4 a = *(const f32x4*)p;
      f32x4 b = *(const f32x4*)(p + 4);
      union { uint32_t u[4]; s16x8 s; } pk;
      pk.u[0] = cvtpk(a[0]*sc, a[1]*sc); pk.u[1] = cvtpk(a[2]*sc, a[3]*sc);
      pk.u[2] = cvtpk(b[0]*sc, b[1]*sc); pk.u[3] = cvtpk(b[2]*sc, b[3]*sc);
      Bh1[j] = pk.s;
    }
    const float bb = (b_ih[n] + b_hh[n]) * sc;
    biasv[j] = (f32x4){bb, bb, bb, bb};
  }

  for (int i = tid; i < 2 * 2 * 4 * HSTRIDE; i += 512) ((uint16_t*)hbuf)[i] = 0;

  float c = 0.f;  // this lane's single cell: (chain, batch lq, col 16w+lr)

  // hoisted LDS offsets (within this chain's buffer)
  const int roff0 = arow * HSTRIDE + 8 * lq;
  const int roff1 = roff0 + 32;
  const int woff  = lq * HSTRIDE + 16 * w + lr;

  // 2-deep x prefetch, running pointer (addresses dup x4; coalescer dedups)
  const float* xbase = x + (size_t)(bm + 4 * chain + arow) * (size_t)T * DD + lq * 8;
  f32x4 xa0 = *(const f32x4*)xbase;        f32x4 xb0 = *(const f32x4*)(xbase + 4);
  f32x4 xa1 = *(const f32x4*)(xbase + DD); f32x4 xb1 = *(const f32x4*)(xbase + DD + 4);
  const float* xp = xbase + 2 * DD;

  __syncthreads();

  auto step = [&](f32x4& xa, f32x4& xb, bool pf,
                  const uint16_t* hr, uint16_t* hw) {
    BAR();  // prev step's h writes visible; global x loads stay in flight

    // h reads for this chain (latency shadowed by pack below + sibling stream)
    s16x8 ah0 = *(const s16x8*)(hr + roff0);
    s16x8 ah1 = *(const s16x8*)(hr + roff1);

    // pack x into A fragment, then issue t+2 prefetch
    union { uint32_t u[4]; s16x8 s; } ax;
    ax.u[0] = cvtpk(xa[0], xa[1]); ax.u[1] = cvtpk(xa[2], xa[3]);
    ax.u[2] = cvtpk(xb[0], xb[1]); ax.u[3] = cvtpk(xb[2], xb[3]);
    if (pf) {
      xa = *(const f32x4*)xp; xb = *(const f32x4*)(xp + 4); xp += DD;
    }

    // MFMAs: x-part (bias in C) then h-parts
    f32x4 acc[4];
    #pragma unroll
    for (int j = 0; j < 4; ++j)
      acc[j] = __builtin_amdgcn_mfma_f32_16x16x32_bf16(ax.s, Bx[j], biasv[j], 0, 0, 0);
    #pragma unroll
    for (int j = 0; j < 4; ++j)
      acc[j] = __builtin_amdgcn_mfma_f32_16x16x32_bf16(ah0, Bh0[j], acc[j], 0, 0, 0);
    #pragma unroll
    for (int j = 0; j < 4; ++j)
      acc[j] = __builtin_amdgcn_mfma_f32_16x16x32_bf16(ah1, Bh1[j], acc[j], 0, 0, 0);

    // gates are lane-local: acc[j][0] (all 4 regs identical; batch = lq)
    float g0 = acc[0][0], g1 = acc[1][0], g2 = acc[2][0], g3 = acc[3][0];

    // single-cell LSTM update (weights pre-scaled by log2e)
    float ig = __builtin_amdgcn_rcpf(1.f + __builtin_amdgcn_exp2f(-g0));
    float fg = __builtin_amdgcn_rcpf(1.f + __builtin_amdgcn_exp2f(-g1));
    float gt = 1.f - 2.f * __builtin_amdgcn_rcpf(1.f + __builtin_amdgcn_exp2f(g2));
    float og = __builtin_amdgcn_rcpf(1.f + __builtin_amdgcn_exp2f(-g3));
    c = fg * c + ig * gt;
    float tc = 1.f - 2.f * __builtin_amdgcn_rcpf(
                 1.f + __builtin_amdgcn_exp2f((2.0f * LOG2E) * c));
    float hv = og * tc;
    hw[woff] = (uint16_t)cvtpk(hv, hv);  // one b16 write per lane
  };

  for (int t = 0; t < T - 2; t += 2) {
    step(xa0, xb0, true, hbuf[0][chain], hbuf[1][chain]);
    step(xa1, xb1, true, hbuf[1][chain], hbuf[0][chain]);
  }
  step(xa0, xb0, false, hbuf[0][chain], hbuf[1][chain]);
  step(xa1, xb1, false, hbuf[1][chain], hbuf[0][chain]);

  __syncthreads();  // final h (bf16) in hbuf[0][chain], linear [row][col]

  // ---- epilogue: logits = h_last @ fc_W^T + fc_b (8 rows x 10 cols) ----
  if (tid < 80) {
    const int m = tid / 10, cl = tid % 10;   // m: 0..7 -> chain m>>2, row m&3
    float s = fc_b[cl];
    const float* wr = fc_W + cl * HH;
    const uint16_t* hm = hbuf[0][m >> 2] + (m & 3) * HSTRIDE;
    #pragma unroll
    for (int k = 0; k < HH; ++k) {
      union { uint32_t u; float f; } v;
      v.u = (uint32_t)hm[k] << 16;
      s += v.f * wr[k];
    }
    out[(size_t)(bm + m) * 10 + cl] = s;
  }
}

extern "C" void kernel_launch(void* const* d_in, const int* in_sizes, int n_in,
                              void* d_out, int out_size, void* d_ws, size_t ws_size,
                              hipStream_t stream) {
  const float* x    = (const float*)d_in[0];
  const float* W_ih = (const float*)d_in[1];
  const float* W_hh = (const float*)d_in[2];
  const float* b_ih = (const float*)d_in[3];
  const float* b_hh = (const float*)d_in[4];
  const float* fc_W = (const float*)d_in[5];
  const float* fc_b = (const float*)d_in[6];
  float* out = (float*)d_out;

  const int B = out_size / 10;            // 2048
  const int T = in_sizes[0] / (B * DD);   // 1024

  dim3 grid(B / 8), block(512);
  hipLaunchKernelGGL(lstm_fused, grid, block, 0, stream,
                     x, W_ih, W_hh, b_ih, b_hh, fc_W, fc_b, out, T);
}

// Round 12
// 374.963 us; speedup vs baseline: 1.5710x; 1.0379x over previous
//
#include <hip/hip_runtime.h>
#include <hip/hip_bf16.h>
#include <stdint.h>

#define DD 32       // input dim
#define HH 64       // hidden dim
#define HSTRIDE 80  // LDS h-row stride in elems (160B)
#define LOG2E 1.44269504088896340736f

typedef float f32x4 __attribute__((ext_vector_type(4)));
typedef short s16x8 __attribute__((ext_vector_type(8)));

// Single-instruction packed f32->bf16 (RNE). Low 16 bits = lo, high = hi.
__device__ __forceinline__ uint32_t cvtpk(float lo, float hi) {
  uint32_t r;
  asm("v_cvt_pk_bf16_f32 %0, %1, %2" : "=v"(r) : "v"(lo), "v"(hi));
  return r;
}

// Relaxed workgroup barrier: order LDS ops only (x-prefetch global loads stay
// in flight). sched_barrier(0) pins the compiler: nothing crosses this point.
#define BAR() do {                                                    \
  asm volatile("s_waitcnt lgkmcnt(0)\n\ts_barrier" ::: "memory");     \
  __builtin_amdgcn_sched_barrier(0);                                  \
} while (0)

// 512 blocks x 4 waves (256 thr). Each block = ONE 4-row chain; wave w owns
// cols 16w..16w+15 for all 4 gates = 4 N-tiles x 3 K-MFMA = 12 MFMA/step.
// A-rows dup x4 (arow=lr>>2) => D rows 4lq+r all map to batch lq => lane
// (lr,lq) owns cell (batch lq, col 16w+lr); gate j = acc[j][0]. 1 cell/lane.
// Same total work as R11, but the 2 waves/SIMD now come from DIFFERENT blocks
// with independent barriers -> phase diversity, MFMA/trans pipes overlap.
__global__ __launch_bounds__(256, 2)
void lstm_fused(const float* __restrict__ x,
                const float* __restrict__ W_ih,
                const float* __restrict__ W_hh,
                const float* __restrict__ b_ih,
                const float* __restrict__ b_hh,
                const float* __restrict__ fc_W,
                const float* __restrict__ fc_b,
                float* __restrict__ out,
                int T)
{
  const int tid   = threadIdx.x;
  const int w     = tid >> 6;      // wave 0..3 -> col group 16w
  const int lane  = tid & 63;
  const int lr    = lane & 15;     // A/D col index within tile
  const int lq    = lane >> 4;     // k-group 0..3; ALSO this lane's batch row
  const int arow  = lr >> 2;       // batch row content of A slot (dup x4)
  const int bm    = blockIdx.x * 4;

  // [buf][row*HSTRIDE]
  __shared__ __align__(16) uint16_t hbuf[2][4 * HSTRIDE];

  // ---- persistent weights: tile j = gate j, cols 16w..16w+15.
  // pre-scaled by log2e (2*log2e for g-gate).
  s16x8 Bx[4], Bh0[4], Bh1[4];
  f32x4 biasv[4];
  #pragma unroll
  for (int j = 0; j < 4; ++j) {
    const int n = 64 * j + 16 * w + lr;
    const float sc = (j == 2) ? (2.0f * LOG2E) : LOG2E;
    {
      const float* p = W_ih + n * DD + lq * 8;
      f32x4 a = *(const f32x4*)p;
      f32x4 b = *(const f32x4*)(p + 4);
      union { uint32_t u[4]; s16x8 s; } pk;
      pk.u[0] = cvtpk(a[0]*sc, a[1]*sc); pk.u[1] = cvtpk(a[2]*sc, a[3]*sc);
      pk.u[2] = cvtpk(b[0]*sc, b[1]*sc); pk.u[3] = cvtpk(b[2]*sc, b[3]*sc);
      Bx[j] = pk.s;
    }
    {
      const float* p = W_hh + n * HH + lq * 8;
      f32x4 a = *(const f32x4*)p;
      f32x4 b = *(const f32x4*)(p + 4);
      union { uint32_t u[4]; s16x8 s; } pk;
      pk.u[0] = cvtpk(a[0]*sc, a[1]*sc); pk.u[1] = cvtpk(a[2]*sc, a[3]*sc);
      pk.u[2] = cvtpk(b[0]*sc, b[1]*sc); pk.u[3] = cvtpk(b[2]*sc, b[3]*sc);
      Bh0[j] = pk.s;
    }
    {
      const float* p = W_hh + n * HH + 32 + lq * 8;
      f32x4 a = *(const f32x4*)p;
      f32x4 b = *(const f32x4*)(p + 4);
      union { uint32_t u[4]; s16x8 s; } pk;
      pk.u[0] = cvtpk(a[0]*sc, a[1]*sc); pk.u[1] = cvtpk(a[2]*sc, a[3]*sc);
      pk.u[2] = cvtpk(b[0]*sc, b[1]*sc); pk.u[3] = cvtpk(b[2]*sc, b[3]*sc);
      Bh1[j] = pk.s;
    }
    const float bb = (b_ih[n] + b_hh[n]) * sc;
    biasv[j] = (f32x4){bb, bb, bb, bb};
  }

  for (int i = tid; i < 2 * 4 * HSTRIDE; i += 256) ((uint16_t*)hbuf)[i] = 0;

  float c = 0.f;  // this lane's single cell: (batch lq, col 16w+lr)

  // hoisted LDS offsets
  const int roff0 = arow * HSTRIDE + 8 * lq;
  const int roff1 = roff0 + 32;
  const int woff  = lq * HSTRIDE + 16 * w + lr;

  // 2-deep x prefetch, running pointer (addresses dup x4; coalescer dedups)
  const float* xbase = x + (size_t)(bm + arow) * (size_t)T * DD + lq * 8;
  f32x4 xa0 = *(const f32x4*)xbase;        f32x4 xb0 = *(const f32x4*)(xbase + 4);
  f32x4 xa1 = *(const f32x4*)(xbase + DD); f32x4 xb1 = *(const f32x4*)(xbase + DD + 4);
  const float* xp = xbase + 2 * DD;

  __syncthreads();

  auto step = [&](f32x4& xa, f32x4& xb, bool pf,
                  const uint16_t* hr, uint16_t* hw) {
    BAR();  // prev step's h writes visible; global x loads stay in flight

    // h reads (latency shadowed by pack below + other-block waves)
    s16x8 ah0 = *(const s16x8*)(hr + roff0);
    s16x8 ah1 = *(const s16x8*)(hr + roff1);

    // pack x into A fragment, then issue t+2 prefetch
    union { uint32_t u[4]; s16x8 s; } ax;
    ax.u[0] = cvtpk(xa[0], xa[1]); ax.u[1] = cvtpk(xa[2], xa[3]);
    ax.u[2] = cvtpk(xb[0], xb[1]); ax.u[3] = cvtpk(xb[2], xb[3]);
    if (pf) {
      xa = *(const f32x4*)xp; xb = *(const f32x4*)(xp + 4); xp += DD;
    }

    // MFMAs: x-part (bias in C) then h-parts
    f32x4 acc[4];
    #pragma unroll
    for (int j = 0; j < 4; ++j)
      acc[j] = __builtin_amdgcn_mfma_f32_16x16x32_bf16(ax.s, Bx[j], biasv[j], 0, 0, 0);
    #pragma unroll
    for (int j = 0; j < 4; ++j)
      acc[j] = __builtin_amdgcn_mfma_f32_16x16x32_bf16(ah0, Bh0[j], acc[j], 0, 0, 0);
    #pragma unroll
    for (int j = 0; j < 4; ++j)
      acc[j] = __builtin_amdgcn_mfma_f32_16x16x32_bf16(ah1, Bh1[j], acc[j], 0, 0, 0);

    // gates are lane-local: acc[j][0] (all 4 regs identical; batch = lq)
    float g0 = acc[0][0], g1 = acc[1][0], g2 = acc[2][0], g3 = acc[3][0];

    // single-cell LSTM update (weights pre-scaled by log2e)
    float ig = __builtin_amdgcn_rcpf(1.f + __builtin_amdgcn_exp2f(-g0));
    float fg = __builtin_amdgcn_rcpf(1.f + __builtin_amdgcn_exp2f(-g1));
    float gt = 1.f - 2.f * __builtin_amdgcn_rcpf(1.f + __builtin_amdgcn_exp2f(g2));
    float og = __builtin_amdgcn_rcpf(1.f + __builtin_amdgcn_exp2f(-g3));
    c = fg * c + ig * gt;
    float tc = 1.f - 2.f * __builtin_amdgcn_rcpf(
                 1.f + __builtin_amdgcn_exp2f((2.0f * LOG2E) * c));
    float hv = og * tc;
    hw[woff] = (uint16_t)cvtpk(hv, hv);  // one b16 write per lane
  };

  for (int t = 0; t < T - 2; t += 2) {
    step(xa0, xb0, true, hbuf[0], hbuf[1]);
    step(xa1, xb1, true, hbuf[1], hbuf[0]);
  }
  step(xa0, xb0, false, hbuf[0], hbuf[1]);
  step(xa1, xb1, false, hbuf[1], hbuf[0]);

  __syncthreads();  // final h (bf16) in hbuf[0], linear [row][col]

  // ---- epilogue: logits = h_last @ fc_W^T + fc_b (4 rows x 10 cols) ----
  if (tid < 40) {
    const int m = tid / 10, cl = tid % 10;
    float s = fc_b[cl];
    const float* wr = fc_W + cl * HH;
    const uint16_t* hm = hbuf[0] + m * HSTRIDE;
    #pragma unroll
    for (int k = 0; k < HH; ++k) {
      union { uint32_t u; float f; } v;
      v.u = (uint32_t)hm[k] << 16;
      s += v.f * wr[k];
    }
    out[(size_t)(bm + m) * 10 + cl] = s;
  }
}

extern "C" void kernel_launch(void* const* d_in, const int* in_sizes, int n_in,
                              void* d_out, int out_size, void* d_ws, size_t ws_size,
                              hipStream_t stream) {
  const float* x    = (const float*)d_in[0];
  const float* W_ih = (const float*)d_in[1];
  const float* W_hh = (const float*)d_in[2];
  const float* b_ih = (const float*)d_in[3];
  const float* b_hh = (const float*)d_in[4];
  const float* fc_W = (const float*)d_in[5];
  const float* fc_b = (const float*)d_in[6];
  float* out = (float*)d_out;

  const int B = out_size / 10;            // 2048
  const int T = in_sizes[0] / (B * DD);   // 1024

  dim3 grid(B / 4), block(256);
  hipLaunchKernelGGL(lstm_fused, grid, block, 0, stream,
                     x, W_ih, W_hh, b_ih, b_hh, fc_W, fc_b, out, T);
}

// Round 13
// 346.390 us; speedup vs baseline: 1.7006x; 1.0825x over previous
//
#include <hip/hip_runtime.h>
#include <hip/hip_bf16.h>
#include <stdint.h>

#define DD 32       // input dim
#define HH 64       // hidden dim
#define HSTRIDE 80  // LDS h-row stride in elems (160B)
#define LOG2E 1.44269504088896340736f

typedef float f32x4 __attribute__((ext_vector_type(4)));
typedef short s16x8 __attribute__((ext_vector_type(8)));

// Single-instruction packed f32->bf16 (RNE). Low 16 bits = lo, high = hi.
__device__ __forceinline__ uint32_t cvtpk(float lo, float hi) {
  uint32_t r;
  asm("v_cvt_pk_bf16_f32 %0, %1, %2" : "=v"(r) : "v"(lo), "v"(hi));
  return r;
}

// Relaxed workgroup barrier: order LDS ops only (x-prefetch global loads stay
// in flight). sched_barrier(0) pins the compiler: nothing crosses this point.
#define BAR() do {                                                    \
  asm volatile("s_waitcnt lgkmcnt(0)\n\ts_barrier" ::: "memory");     \
  __builtin_amdgcn_sched_barrier(0);                                  \
} while (0)

// 512 blocks x 4 waves (256 thr). Each block = ONE 4-row chain; wave w owns
// cols 16w..16w+15 for all 4 gates = 4 N-tiles x 3 K-MFMA = 12 MFMA/step.
// A-rows dup x4 (arow=lr>>2) => D rows 4lq+r all map to batch lq => lane
// (lr,lq) owns cell (batch lq, col 16w+lr); gate j = acc[j][0]. 1 cell/lane.
// Cell update uses common-denominator forms: 7 trans/cell (5 exp2 + 2 rcp)
// instead of 10 — trans issue (16cy/instr wave64) was ~36% of the wall.
__global__ __launch_bounds__(256, 2)
void lstm_fused(const float* __restrict__ x,
                const float* __restrict__ W_ih,
                const float* __restrict__ W_hh,
                const float* __restrict__ b_ih,
                const float* __restrict__ b_hh,
                const float* __restrict__ fc_W,
                const float* __restrict__ fc_b,
                float* __restrict__ out,
                int T)
{
  const int tid   = threadIdx.x;
  const int w     = tid >> 6;      // wave 0..3 -> col group 16w
  const int lane  = tid & 63;
  const int lr    = lane & 15;     // A/D col index within tile
  const int lq    = lane >> 4;     // k-group 0..3; ALSO this lane's batch row
  const int arow  = lr >> 2;       // batch row content of A slot (dup x4)
  const int bm    = blockIdx.x * 4;

  // [buf][row*HSTRIDE]
  __shared__ __align__(16) uint16_t hbuf[2][4 * HSTRIDE];

  // ---- persistent weights: tile j = gate j, cols 16w..16w+15.
  // pre-scaled by log2e (2*log2e for g-gate).
  s16x8 Bx[4], Bh0[4], Bh1[4];
  f32x4 biasv[4];
  #pragma unroll
  for (int j = 0; j < 4; ++j) {
    const int n = 64 * j + 16 * w + lr;
    const float sc = (j == 2) ? (2.0f * LOG2E) : LOG2E;
    {
      const float* p = W_ih + n * DD + lq * 8;
      f32x4 a = *(const f32x4*)p;
      f32x4 b = *(const f32x4*)(p + 4);
      union { uint32_t u[4]; s16x8 s; } pk;
      pk.u[0] = cvtpk(a[0]*sc, a[1]*sc); pk.u[1] = cvtpk(a[2]*sc, a[3]*sc);
      pk.u[2] = cvtpk(b[0]*sc, b[1]*sc); pk.u[3] = cvtpk(b[2]*sc, b[3]*sc);
      Bx[j] = pk.s;
    }
    {
      const float* p = W_hh + n * HH + lq * 8;
      f32x4 a = *(const f32x4*)p;
      f32x4 b = *(const f32x4*)(p + 4);
      union { uint32_t u[4]; s16x8 s; } pk;
      pk.u[0] = cvtpk(a[0]*sc, a[1]*sc); pk.u[1] = cvtpk(a[2]*sc, a[3]*sc);
      pk.u[2] = cvtpk(b[0]*sc, b[1]*sc); pk.u[3] = cvtpk(b[2]*sc, b[3]*sc);
      Bh0[j] = pk.s;
    }
    {
      const float* p = W_hh + n * HH + 32 + lq * 8;
      f32x4 a = *(const f32x4*)p;
      f32x4 b = *(const f32x4*)(p + 4);
      union { uint32_t u[4]; s16x8 s; } pk;
      pk.u[0] = cvtpk(a[0]*sc, a[1]*sc); pk.u[1] = cvtpk(a[2]*sc, a[3]*sc);
      pk.u[2] = cvtpk(b[0]*sc, b[1]*sc); pk.u[3] = cvtpk(b[2]*sc, b[3]*sc);
      Bh1[j] = pk.s;
    }
    const float bb = (b_ih[n] + b_hh[n]) * sc;
    biasv[j] = (f32x4){bb, bb, bb, bb};
  }

  for (int i = tid; i < 2 * 4 * HSTRIDE; i += 256) ((uint16_t*)hbuf)[i] = 0;

  float c = 0.f;  // this lane's single cell: (batch lq, col 16w+lr)

  // hoisted LDS offsets
  const int roff0 = arow * HSTRIDE + 8 * lq;
  const int roff1 = roff0 + 32;
  const int woff  = lq * HSTRIDE + 16 * w + lr;

  // 2-deep x prefetch, running pointer (addresses dup x4; coalescer dedups)
  const float* xbase = x + (size_t)(bm + arow) * (size_t)T * DD + lq * 8;
  f32x4 xa0 = *(const f32x4*)xbase;        f32x4 xb0 = *(const f32x4*)(xbase + 4);
  f32x4 xa1 = *(const f32x4*)(xbase + DD); f32x4 xb1 = *(const f32x4*)(xbase + DD + 4);
  const float* xp = xbase + 2 * DD;

  __syncthreads();

  auto step = [&](f32x4& xa, f32x4& xb, bool pf,
                  const uint16_t* hr, uint16_t* hw) {
    BAR();  // prev step's h writes visible; global x loads stay in flight

    // h reads (latency shadowed by pack below + other-block waves)
    s16x8 ah0 = *(const s16x8*)(hr + roff0);
    s16x8 ah1 = *(const s16x8*)(hr + roff1);

    // pack x into A fragment, then issue t+2 prefetch
    union { uint32_t u[4]; s16x8 s; } ax;
    ax.u[0] = cvtpk(xa[0], xa[1]); ax.u[1] = cvtpk(xa[2], xa[3]);
    ax.u[2] = cvtpk(xb[0], xb[1]); ax.u[3] = cvtpk(xb[2], xb[3]);
    if (pf) {
      xa = *(const f32x4*)xp; xb = *(const f32x4*)(xp + 4); xp += DD;
    }

    // MFMAs: x-part (bias in C) then h-parts
    f32x4 acc[4];
    #pragma unroll
    for (int j = 0; j < 4; ++j)
      acc[j] = __builtin_amdgcn_mfma_f32_16x16x32_bf16(ax.s, Bx[j], biasv[j], 0, 0, 0);
    #pragma unroll
    for (int j = 0; j < 4; ++j)
      acc[j] = __builtin_amdgcn_mfma_f32_16x16x32_bf16(ah0, Bh0[j], acc[j], 0, 0, 0);
    #pragma unroll
    for (int j = 0; j < 4; ++j)
      acc[j] = __builtin_amdgcn_mfma_f32_16x16x32_bf16(ah1, Bh1[j], acc[j], 0, 0, 0);

    // gates are lane-local: acc[j][0] (all 4 regs identical; batch = lq).
    // g0=i, g1=f, g3=o (xlog2e); g2=g (x2log2e).
    float g0 = acc[0][0], g1 = acc[1][0], g2 = acc[2][0], g3 = acc[3][0];

    // 7-trans cell update (common-denominator forms; algebraically equal to
    //  sigma(i)tanh(g), sigma(f), sigma(o)tanh(c)):
    //  c' = [c(1+A)(1+Q) + (Q-1)(1+F)] / [(1+A)(1+Q)(1+F)]
    //  h  = (S-1) / [(1+O)(1+S)], S = exp2(2log2e * c')
    float A = __builtin_amdgcn_exp2f(-g0);
    float F = __builtin_amdgcn_exp2f(-g1);
    float Q = __builtin_amdgcn_exp2f(g2);
    float O = __builtin_amdgcn_exp2f(-g3);
    float u  = 1.f + A;
    float v  = 1.f + Q;
    float wf = 1.f + F;
    float M  = u * v;
    float D  = M * wf;
    float num = c * M + (Q - 1.f) * wf;
    float r  = __builtin_amdgcn_rcpf(D);
    c = num * r;
    // clamp the tanh(c) exp argument: c accumulates, exp2 may overflow;
    // tanh saturates to +-1 identically in this range.
    float sarg = fminf(fmaxf((2.0f * LOG2E) * c, -80.f), 80.f);
    float S  = __builtin_amdgcn_exp2f(sarg);
    float r2 = __builtin_amdgcn_rcpf((1.f + O) * (1.f + S));
    float hv = (S - 1.f) * r2;
    hw[woff] = (uint16_t)cvtpk(hv, hv);  // one b16 write per lane
  };

  for (int t = 0; t < T - 2; t += 2) {
    step(xa0, xb0, true, hbuf[0], hbuf[1]);
    step(xa1, xb1, true, hbuf[1], hbuf[0]);
  }
  step(xa0, xb0, false, hbuf[0], hbuf[1]);
  step(xa1, xb1, false, hbuf[1], hbuf[0]);

  __syncthreads();  // final h (bf16) in hbuf[0], linear [row][col]

  // ---- epilogue: logits = h_last @ fc_W^T + fc_b (4 rows x 10 cols) ----
  if (tid < 40) {
    const int m = tid / 10, cl = tid % 10;
    float s = fc_b[cl];
    const float* wr = fc_W + cl * HH;
    const uint16_t* hm = hbuf[0] + m * HSTRIDE;
    #pragma unroll
    for (int k = 0; k < HH; ++k) {
      union { uint32_t u; float f; } v;
      v.u = (uint32_t)hm[k] << 16;
      s += v.f * wr[k];
    }
    out[(size_t)(bm + m) * 10 + cl] = s;
  }
}

extern "C" void kernel_launch(void* const* d_in, const int* in_sizes, int n_in,
                              void* d_out, int out_size, void* d_ws, size_t ws_size,
                              hipStream_t stream) {
  const float* x    = (const float*)d_in[0];
  const float* W_ih = (const float*)d_in[1];
  const float* W_hh = (const float*)d_in[2];
  const float* b_ih = (const float*)d_in[3];
  const float* b_hh = (const float*)d_in[4];
  const float* fc_W = (const float*)d_in[5];
  const float* fc_b = (const float*)d_in[6];
  float* out = (float*)d_out;

  const int B = out_size / 10;            // 2048
  const int T = in_sizes[0] / (B * DD);   // 1024

  dim3 grid(B / 4), block(256);
  hipLaunchKernelGGL(lstm_fused, grid, block, 0, stream,
                     x, W_ih, W_hh, b_ih, b_hh, fc_W, fc_b, out, T);
}